// Round 14
// baseline (31.386 us; speedup 1.0000x reference)
//
#include <hip/hip_runtime.h>
#include <hip/hip_bf16.h>

// Oja scan, reformulated. G[b][n][t] = row_n . x_t for n in [0,1088):
// rows 0..1023 = W0 rows, rows 1024..1087 = X rows (=> S = X X^T).
// Scan: exact projected Oja recurrence on u[j] = W_t . x_j:
//   y_t = sigmoid(u[t]);  u <- (1-lr*y^2)*u + (lr*y)*S[t,:]
// R14: K-split across blocks (ks=4 x K=256) -> grid 2176 (~8 blocks/CU
// available, ~4 resident) so neighbor blocks hide each other's stage-drain
// (the R6-R13 one-shot blocks at <=2/CU could not). Tiny 8.4 KB LDS panel,
// 8 MFMA/wave, fp32 partials Gpart[4]; scan sums the 4 partials on read.

#define BB 8
#define TT 64
#define NI 1024
#define NO 1024
#define NTOT 1088                    // 1024 W rows + 64 X rows
#define PSTR ((size_t)BB * NTOT * TT)  // floats per K-partial = 557056

typedef __attribute__((ext_vector_type(8))) short bf16x8;
typedef __attribute__((ext_vector_type(4))) float f32x4;

__device__ __forceinline__ short f2bf(float f) {
    __hip_bfloat16 h = __float2bfloat16(f);
    return __builtin_bit_cast(short, h);
}

// ---------- Kernel 0: X (f32, 0.52M elems) -> bf16 ----------
__global__ __launch_bounds__(256)
void xcvt_kernel(const float* __restrict__ X, ushort* __restrict__ Xb16)
{
    const int i = blockIdx.x * 256 + threadIdx.x;   // float4 index, 131072 total
    const float4 v = *reinterpret_cast<const float4*>(X + (size_t)i * 4);
    short4 s;
    s.x = f2bf(v.x); s.y = f2bf(v.y); s.z = f2bf(v.z); s.w = f2bf(v.w);
    *reinterpret_cast<short4*>(Xb16 + (size_t)i * 4) = s;
}

// ---------- Kernel 1: Gpart[ks][b][n][t] partial GEMM ----------
// Grid 2176: ks = bid&3, job = bid>>2 (b = job&7, nt = job>>3).
// Block 256 thr = 4 waves; wave w -> t-tile w*16; K-slice = ks*256..+256.
__global__ __launch_bounds__(256, 4)
void gemmp_kernel(const float* __restrict__ X, const float* __restrict__ W0,
                  const ushort* __restrict__ Xb16, float* __restrict__ Gp)
{
    __shared__ __align__(16) ushort As[16 * 264];   // 8448 B (pad 8 shorts/row)

    const int tid  = threadIdx.x;
    const int lane = tid & 63;
    const int wave = tid >> 6;
    const int ks  = blockIdx.x & 3;
    const int job = blockIdx.x >> 2;     // 0..543
    const int b   = job & 7;
    const int nt  = job >> 3;            // 0..67
    const int n0  = nt * 16;
    const int t0  = wave * 16;

    const int r  = lane & 15;            // fragment row
    const int kb = lane >> 4;            // k-block 0..3 (8 k's each)

    // ---- B-frags -> registers (bf16, L2-hot; 8 x 16B) ----
    bf16x8 breg[8];
    {
        const ushort* __restrict__ Bbase =
            Xb16 + ((size_t)b * TT + t0 + r) * NI + ks * 256 + kb * 8;
#pragma unroll
        for (int kk = 0; kk < 8; ++kk)
            breg[kk] = *reinterpret_cast<const bf16x8*>(Bbase + kk * 32);
    }

    // ---- A stage: 16 rows x 256 f32 -> bf16 LDS (4 float4/thread) ----
    const float* __restrict__ Abase =
        (((n0) < NO) ? (W0 + ((size_t)b * NO + n0) * NI)
                     : (X + ((size_t)b * TT + (n0 - NO)) * NI)) + ks * 256;
    {
        const int j = tid >> 4;          // row 0..15
        const int x = tid & 15;          // 16-float slice within row
        const float* sr = Abase + (size_t)j * NI + x * 16;
        const float4 v0 = *reinterpret_cast<const float4*>(sr);
        const float4 v1 = *reinterpret_cast<const float4*>(sr + 4);
        const float4 v2 = *reinterpret_cast<const float4*>(sr + 8);
        const float4 v3 = *reinterpret_cast<const float4*>(sr + 12);
        bf16x8 s0, s1;
        s0[0] = f2bf(v0.x); s0[1] = f2bf(v0.y); s0[2] = f2bf(v0.z); s0[3] = f2bf(v0.w);
        s0[4] = f2bf(v1.x); s0[5] = f2bf(v1.y); s0[6] = f2bf(v1.z); s0[7] = f2bf(v1.w);
        s1[0] = f2bf(v2.x); s1[1] = f2bf(v2.y); s1[2] = f2bf(v2.z); s1[3] = f2bf(v2.w);
        s1[4] = f2bf(v3.x); s1[5] = f2bf(v3.y); s1[6] = f2bf(v3.z); s1[7] = f2bf(v3.w);
        *reinterpret_cast<bf16x8*>(&As[j * 264 + x * 16])     = s0;
        *reinterpret_cast<bf16x8*>(&As[j * 264 + x * 16 + 8]) = s1;
    }
    __syncthreads();

    // ---- 8 x (ds_read_b128 + MFMA) ----
    f32x4 acc = {0.f, 0.f, 0.f, 0.f};
    const ushort* __restrict__ Ap = &As[r * 264 + kb * 8];
#pragma unroll
    for (int kk = 0; kk < 8; ++kk) {
        const bf16x8 a = *reinterpret_cast<const bf16x8*>(Ap + kk * 32);
        acc = __builtin_amdgcn_mfma_f32_16x16x32_bf16(a, breg[kk], acc, 0, 0, 0);
    }

    // D layout: col t = lane&15, row n = (lane>>4)*4 + rr   [m89-verified]
    const int tcol = lane & 15;
    const int mrow = (lane >> 4) * 4;
    float* __restrict__ Gout = Gp + (size_t)ks * PSTR;
#pragma unroll
    for (int rr = 0; rr < 4; ++rr)
        Gout[((size_t)b * NTOT + n0 + mrow + rr) * TT + t0 + tcol] = acc[rr];
}

// ---------- Kernel 2: lane-parallel projected-Oja scan ----------
// 512 blocks x 256 thr (4 waves). Block: batch b = bid&7, 16 o-rows.
// Reads 4 K-partials and sums (fp32).
__global__ __launch_bounds__(256, 8)
void scan_kernel(const float* __restrict__ Gp, float* __restrict__ out)
{
    __shared__ float Sl[TT][TT];
    __shared__ float ybuf[16][68];

    const int tid  = threadIdx.x;
    const int lane = tid & 63;
    const int wave = tid >> 6;
    const int b  = blockIdx.x & 7;
    const int o0 = (blockIdx.x >> 3) * 16;

    // stage S[b]: sum of 4 partials of rows 1024..1087
    {
        const size_t off = ((size_t)b * NTOT + NO) * TT;
        const float4* p0 = reinterpret_cast<const float4*>(Gp + 0 * PSTR + off);
        const float4* p1 = reinterpret_cast<const float4*>(Gp + 1 * PSTR + off);
        const float4* p2 = reinterpret_cast<const float4*>(Gp + 2 * PSTR + off);
        const float4* p3 = reinterpret_cast<const float4*>(Gp + 3 * PSTR + off);
        float4* dst = reinterpret_cast<float4*>(&Sl[0][0]);
#pragma unroll
        for (int q = 0; q < 4; ++q) {
            const int idx = tid + q * 256;
            const float4 a = p0[idx], c = p1[idx], d = p2[idx], e = p3[idx];
            float4 s;
            s.x = a.x + c.x + d.x + e.x;
            s.y = a.y + c.y + d.y + e.y;
            s.z = a.z + c.z + d.z + e.z;
            s.w = a.w + c.w + d.w + e.w;
            dst[idx] = s;
        }
    }

    const int r  = lane & 3;
    const int jb = lane >> 2;
    const int row = o0 + wave * 4 + r;

    // u init: sum of 4 partials
    float u0, u1, u2, u3;
    {
        const size_t go = ((size_t)b * NTOT + row) * TT + jb * 4;
        const float4 a = *reinterpret_cast<const float4*>(Gp + 0 * PSTR + go);
        const float4 c = *reinterpret_cast<const float4*>(Gp + 1 * PSTR + go);
        const float4 d = *reinterpret_cast<const float4*>(Gp + 2 * PSTR + go);
        const float4 e = *reinterpret_cast<const float4*>(Gp + 3 * PSTR + go);
        u0 = a.x + c.x + d.x + e.x;
        u1 = a.y + c.y + d.y + e.y;
        u2 = a.z + c.z + d.z + e.z;
        u3 = a.w + c.w + d.w + e.w;
    }

    __syncthreads();

    const float lr   = 1.0f / 1024.0f;
    const float nL2E = -1.44269504f;
    float y0 = 0.f, y1 = 0.f, y2 = 0.f, y3 = 0.f;

#pragma unroll
    for (int t = 0; t < TT; ++t) {
        const int srcl = (t & 0x3C) | r;
        const float uv = ((t & 3) == 0) ? u0 : ((t & 3) == 1) ? u1
                       : ((t & 3) == 2) ? u2 : u3;
        const float pre = __shfl(uv, srcl, 64);

        const float e = __builtin_amdgcn_exp2f(pre * nL2E);
        const float y = __builtin_amdgcn_rcpf(1.0f + e);

        const bool own = (jb == (t >> 2));
        if ((t & 3) == 0) y0 = own ? y : y0;
        if ((t & 3) == 1) y1 = own ? y : y1;
        if ((t & 3) == 2) y2 = own ? y : y2;
        if ((t & 3) == 3) y3 = own ? y : y3;

        const float c2 = lr * y;
        const float c1 = fmaf(-c2, y, 1.0f);

        const float4 s = *reinterpret_cast<const float4*>(&Sl[t][jb * 4]);
        u0 = fmaf(c1, u0, c2 * s.x);
        u1 = fmaf(c1, u1, c2 * s.y);
        u2 = fmaf(c1, u2, c2 * s.z);
        u3 = fmaf(c1, u3, c2 * s.w);
    }

    {
        float4 yv; yv.x = y0; yv.y = y1; yv.z = y2; yv.w = y3;
        *reinterpret_cast<float4*>(&ybuf[wave * 4 + r][jb * 4]) = yv;
    }
    __syncthreads();

    {
        const int t = tid >> 2;
        const int g = tid & 3;
        float4 ov;
        ov.x = ybuf[g * 4 + 0][t];
        ov.y = ybuf[g * 4 + 1][t];
        ov.z = ybuf[g * 4 + 2][t];
        ov.w = ybuf[g * 4 + 3][t];
        *reinterpret_cast<float4*>(
            &out[(size_t)b * TT * NO + (size_t)t * NO + o0 + g * 4]) = ov;
    }
}

extern "C" void kernel_launch(void* const* d_in, const int* in_sizes, int n_in,
                              void* d_out, int out_size, void* d_ws, size_t ws_size,
                              hipStream_t stream) {
    const float* X  = (const float*)d_in[0];   // [8][64][1024]
    const float* W0 = (const float*)d_in[1];   // [8][1024][1024]
    float* out = (float*)d_out;                // [8][64][1024]

    float*  Gp   = (float*)d_ws;                          // 4 x 557056 f32 = 8,912,896 B
    ushort* Xb16 = (ushort*)((char*)d_ws + 8912896);      // 1,048,576 B

    xcvt_kernel<<<512, 256, 0, stream>>>(X, Xb16);
    gemmp_kernel<<<4 * 544, 256, 0, stream>>>(X, W0, Xb16, Gp);
    scan_kernel<<<512, 256, 0, stream>>>(Gp, out);
}